// Round 3
// baseline (1273.208 us; speedup 1.0000x reference)
//
#include <hip/hip_runtime.h>

// DGP-RF embeddings, fused MFMA implementation. Round 3.
// R3 changes vs R2:
//  (a) X tile loads are NON-TEMPORAL: X is single-use streaming data; in R2 it
//      evicted the 1.75 MB weight set from the 4 MB/XCD L2 (FETCH x3.3 at 3
//      blocks/CU) and weight-load latency doubled per-WG time.
//  (b) T3 LDS table eliminated: vo = v@(W2mu^2+W2var)^T + m^2@W2var^T, with
//      W2b = W2mu^2+W2var precomputed in bf16 and sq(Tm) recomputed in regs.
//      LDS 43.5 KB -> 33.6 KB -> 4 blocks/CU (16 waves).
//  (c) fragment squaring via v_pk_mul_f32 + round-half-up pack (7 ops/pair,
//      half of R2's per-element RNE cost).

#define NPTS   131072
#define SGRP   16384
#define DIN    256
#define NRF    1024
#define DOUT   128

#define XLD    264   // 256 + 8 pad (16B-aligned rows)
#define TLD    136   // 128 + 8 pad

typedef __attribute__((ext_vector_type(8))) short bf16x8;
typedef __attribute__((ext_vector_type(4))) float f32x4;
typedef __attribute__((ext_vector_type(2))) float f32x2;
typedef __attribute__((ext_vector_type(4))) float f32x4v;

__device__ __forceinline__ unsigned short f2bf(float f) {
  unsigned u = __float_as_uint(f);
  u += 0x7fffu + ((u >> 16) & 1u);   // round-to-nearest-even
  return (unsigned short)(u >> 16);
}

__device__ __forceinline__ float fast_rcp(float x) {
#if __has_builtin(__builtin_amdgcn_rcpf)
  return __builtin_amdgcn_rcpf(x);
#else
  return 1.0f / x;
#endif
}
__device__ __forceinline__ float fast_rsq(float x) {
#if __has_builtin(__builtin_amdgcn_rsqf)
  return __builtin_amdgcn_rsqf(x);
#else
  return rsqrtf(x);
#endif
}
__device__ __forceinline__ float fast_exp2(float x) {
#if __has_builtin(__builtin_amdgcn_exp2f)
  return __builtin_amdgcn_exp2f(x);
#else
  return exp2f(x);
#endif
}

// elementwise square of a bf16x8 fragment; pk_mul + round-half-up pack.
__device__ __forceinline__ bf16x8 sq_frag(bf16x8 a) {
  union { bf16x8 h; unsigned u[4]; } in, out;
  in.h = a;
#pragma unroll
  for (int i = 0; i < 4; ++i) {
    unsigned w = in.u[i];
    f32x2 f;
    f[0] = __uint_as_float(w << 16);
    f[1] = __uint_as_float(w & 0xffff0000u);
    f32x2 s = f * f;                                   // v_pk_mul_f32
    unsigned lo = (__float_as_uint(s[0]) + 0x8000u) >> 16;
    unsigned hi = (__float_as_uint(s[1]) + 0x8000u) & 0xffff0000u;
    out.u[i] = hi | lo;
  }
  return out.h;
}

// Exact Gaussian-ReLU moments. Phi via Abramowitz-Stegun 7.1.26 (|err|<1.5e-7),
// sharing one exp2 between erf tail and the pdf.
__device__ __forceinline__ void relu_moments(float mu, float v,
                                             float& mo, float& vo) {
  float vpe = v + 1e-8f;
  float rsq = fast_rsq(vpe);
  float s   = vpe * rsq;
  float z   = mu * rsq;
  float E   = fast_exp2(-0.7213475204444817f * z * z);  // exp(-z^2/2)
  float x   = 0.70710678118654752f * fabsf(z);
  float t   = fast_rcp(fmaf(0.3275911f, x, 1.0f));
  float poly = t * fmaf(t, fmaf(t, fmaf(t, fmaf(t, 1.061405429f, -1.453152027f),
                                        1.421413741f), -0.284496736f), 0.254829592f);
  float q   = 0.5f * poly * E;
  float Phi = (z >= 0.0f) ? (1.0f - q) : q;
  float phi = 0.3989422804014327f * E;
  float sphi = s * phi;
  mo = fmaf(mu, Phi, sphi);
  float ey2 = fmaf(fmaf(mu, mu, v), Phi, mu * sphi);
  vo = fmaxf(fmaf(-mo, mo, ey2), 1e-6f);
}

// ---------------- kernel 0: detect whether X_idx is int32 or int64 -------------
__global__ void detect_idx_kernel(const unsigned* __restrict__ raw,
                                  int* __restrict__ flag) {
  __shared__ int any_nz;
  if (threadIdx.x == 0) any_nz = 0;
  __syncthreads();
  if (raw[2 * threadIdx.x + 1] != 0u) atomicOr(&any_nz, 1);
  __syncthreads();
  if (threadIdx.x == 0) *flag = (any_nz == 0) ? 1 : 0;   // 1 => int64
}

// ---------------- kernel 1: convert weights to bf16 ---------------------------
// w2b = W2mu^2 + W2var  (folds the T3 operand into an existing B array)
__global__ __launch_bounds__(256) void convert_kernel(
    const float* __restrict__ W1mu, const float* __restrict__ W1var,
    const float* __restrict__ W2mu, const float* __restrict__ W2var,
    unsigned short* __restrict__ w1mu_bf, unsigned short* __restrict__ w1var_bf,
    unsigned short* __restrict__ w2mu_bf, unsigned short* __restrict__ w2b_bf,
    unsigned short* __restrict__ w2var_bf) {
  int i = blockIdx.x * 256 + threadIdx.x;      // grid covers 262144 exactly
  w1mu_bf[i]  = f2bf(W1mu[i]);
  w1var_bf[i] = f2bf(W1var[i]);
  if (i < NRF * DOUT) {
    float m = W2mu[i];
    float v = W2var[i];
    w2mu_bf[i]  = f2bf(m);
    w2b_bf[i]   = f2bf(fmaf(m, m, v));
    w2var_bf[i] = f2bf(v);
  }
}

// ---------------- kernel 2: fused DGP-RF block --------------------------------
__global__ __launch_bounds__(256, 4) void fused_kernel(
    const float* __restrict__ X,
    const unsigned* __restrict__ Xidx_raw,
    const unsigned short* __restrict__ W1mu, const unsigned short* __restrict__ W1var,
    const unsigned short* __restrict__ W2mu, const unsigned short* __restrict__ W2b,
    const unsigned short* __restrict__ W2var,
    const int* __restrict__ flag64,
    float* __restrict__ acc_means,   // [S,128] accumulates prec*mo
    float* __restrict__ acc_vars) {  // [S,128] accumulates prec
  __shared__ unsigned short Xb[32 * XLD];
  __shared__ unsigned short Tm[32 * TLD];
  __shared__ unsigned short Tv[32 * TLD];
  __shared__ int sidx[32];

  const int tid = threadIdx.x;
  const int p0  = blockIdx.x * 32;
  const int is64 = *flag64;

  if (tid < 32) {
    int p = p0 + tid;
    sidx[tid] = (int)(is64 ? Xidx_raw[2 * (size_t)p] : Xidx_raw[p]);
  }
  // stage X tile as bf16, 8 float4 per thread; non-temporal (single-use stream,
  // must not evict the L2-resident weight set)
#pragma unroll
  for (int i = 0; i < 8; ++i) {
    int idx4 = i * 256 + tid;       // 0..2047 (32 rows x 64 float4)
    int row  = idx4 >> 6;
    int c4   = idx4 & 63;
    f32x4v xv = __builtin_nontemporal_load(
        (const f32x4v*)(X + (size_t)(p0 + row) * DIN + c4 * 4));
    int off = row * XLD + c4 * 4;
    ushort4 b;
    b.x = f2bf(xv[0]); b.y = f2bf(xv[1]); b.z = f2bf(xv[2]); b.w = f2bf(xv[3]);
    *(ushort4*)(Xb + off) = b;
  }
  __syncthreads();

  const int lane = tid & 63;
  const int wave = tid >> 6;
  const int l16  = lane & 15;
  const int quad = lane >> 4;

  f32x4 acc_mo[2][2], acc_vo[2][2];
#pragma unroll
  for (int mt = 0; mt < 2; ++mt)
#pragma unroll
    for (int j = 0; j < 2; ++j) {
      acc_mo[mt][j] = (f32x4){0.f, 0.f, 0.f, 0.f};
      acc_vo[mt][j] = (f32x4){0.f, 0.f, 0.f, 0.f};
    }

#pragma unroll 1
  for (int c = 0; c < 8; ++c) {
    // ---- layer 1: m,v chunk [32 x 128] ----
    f32x4 am[2][2], av[2][2];
#pragma unroll
    for (int mt = 0; mt < 2; ++mt)
#pragma unroll
      for (int nt = 0; nt < 2; ++nt) {
        am[mt][nt] = (f32x4){0.f, 0.f, 0.f, 0.f};
        av[mt][nt] = (f32x4){0.f, 0.f, 0.f, 0.f};
      }
#pragma unroll
    for (int k = 0; k < 8; ++k) {
      bf16x8 bmu[2], bvr[2];
#pragma unroll
      for (int nt = 0; nt < 2; ++nt) {
        int n = c * 128 + (wave * 2 + nt) * 16 + l16;
        size_t off = (size_t)n * DIN + k * 32 + quad * 8;
        bmu[nt] = *(const bf16x8*)(W1mu + off);
        bvr[nt] = *(const bf16x8*)(W1var + off);
      }
#pragma unroll
      for (int mt = 0; mt < 2; ++mt) {
        int aoff = (mt * 16 + l16) * XLD + k * 32 + quad * 8;
        bf16x8 ax = *(const bf16x8*)(Xb + aoff);
        bf16x8 aq = sq_frag(ax);          // X^2 fragment, in registers
#pragma unroll
        for (int nt = 0; nt < 2; ++nt) {
          am[mt][nt] = __builtin_amdgcn_mfma_f32_16x16x32_bf16(ax, bmu[nt], am[mt][nt], 0, 0, 0);
          av[mt][nt] = __builtin_amdgcn_mfma_f32_16x16x32_bf16(aq, bvr[nt], av[mt][nt], 0, 0, 0);
        }
      }
    }
    // ---- ReLU moments, write m', v' to LDS (C-layout -> A-layout) ----
#pragma unroll
    for (int mt = 0; mt < 2; ++mt)
#pragma unroll
      for (int nt = 0; nt < 2; ++nt) {
        int col = (wave * 2 + nt) * 16 + l16;
#pragma unroll
        for (int r = 0; r < 4; ++r) {
          float mo, vo;
          relu_moments(am[mt][nt][r], av[mt][nt][r], mo, vo);
          int row = mt * 16 + quad * 4 + r;
          int o = row * TLD + col;
          Tm[o] = f2bf(mo); Tv[o] = f2bf(vo);
        }
      }
    __syncthreads();
    // ---- layer 2: accumulate mo,vo over this chunk's 128 RFs ----
#pragma unroll
    for (int k2 = 0; k2 < 4; ++k2) {
      bf16x8 b2m[2], b2b[2], b2v[2];
#pragma unroll
      for (int j = 0; j < 2; ++j) {
        int n = (wave * 2 + j) * 16 + l16;
        size_t off = (size_t)n * NRF + c * 128 + k2 * 32 + quad * 8;
        b2m[j] = *(const bf16x8*)(W2mu + off);
        b2b[j] = *(const bf16x8*)(W2b + off);
        b2v[j] = *(const bf16x8*)(W2var + off);
      }
#pragma unroll
      for (int mt = 0; mt < 2; ++mt) {
        int aoff = (mt * 16 + l16) * TLD + k2 * 32 + quad * 8;
        bf16x8 fam = *(const bf16x8*)(Tm + aoff);
        bf16x8 fav = *(const bf16x8*)(Tv + aoff);
        bf16x8 fsq = sq_frag(fam);        // m'^2 fragment, in registers
#pragma unroll
        for (int j = 0; j < 2; ++j) {
          acc_mo[mt][j] = __builtin_amdgcn_mfma_f32_16x16x32_bf16(fam, b2m[j], acc_mo[mt][j], 0, 0, 0);
          acc_vo[mt][j] = __builtin_amdgcn_mfma_f32_16x16x32_bf16(fav, b2b[j], acc_vo[mt][j], 0, 0, 0);
          acc_vo[mt][j] = __builtin_amdgcn_mfma_f32_16x16x32_bf16(fsq, b2v[j], acc_vo[mt][j], 0, 0, 0);
        }
      }
    }
    __syncthreads();
  }

  // ---- epilogue: precision-weighted scatter ----
#pragma unroll
  for (int mt = 0; mt < 2; ++mt)
#pragma unroll
    for (int j = 0; j < 2; ++j) {
      int dim = (wave * 2 + j) * 16 + l16;
#pragma unroll
      for (int r = 0; r < 4; ++r) {
        int prow = mt * 16 + quad * 4 + r;
        float mo = acc_mo[mt][j][r];
        float vo = acc_vo[mt][j][r];
        float prec = fast_rcp(vo);
        size_t o = (size_t)sidx[prow] * DOUT + dim;
        unsafeAtomicAdd(acc_means + o, prec * mo);
        unsafeAtomicAdd(acc_vars + o, prec);
      }
    }
}

// ---------------- kernel 3: finalize ------------------------------------------
__global__ __launch_bounds__(256) void finalize_kernel(float* __restrict__ means,
                                                       float* __restrict__ vars) {
  int i = blockIdx.x * 256 + threadIdx.x;   // covers S*DOUT exactly
  float p  = vars[i];
  float pm = means[i];
  float var = 1.0f / p;
  means[i] = pm * var;
  vars[i]  = var;
}

extern "C" void kernel_launch(void* const* d_in, const int* in_sizes, int n_in,
                              void* d_out, int out_size, void* d_ws, size_t ws_size,
                              hipStream_t stream) {
  const float*    X     = (const float*)d_in[0];
  const unsigned* Xidx  = (const unsigned*)d_in[1];
  const float*    W1mu  = (const float*)d_in[2];
  const float*    W1var = (const float*)d_in[3];
  const float*    W2mu  = (const float*)d_in[4];
  const float*    W2var = (const float*)d_in[5];
  float* out = (float*)d_out;

  unsigned short* w1mu_bf  = (unsigned short*)d_ws;
  unsigned short* w1var_bf = w1mu_bf + NRF * DIN;       // 262144
  unsigned short* w2mu_bf  = w1var_bf + NRF * DIN;
  unsigned short* w2b_bf   = w2mu_bf + NRF * DOUT;      // 131072
  unsigned short* w2var_bf = w2b_bf + NRF * DOUT;
  int* flag = (int*)(w2var_bf + NRF * DOUT);

  hipMemsetAsync(d_out, 0, (size_t)out_size * sizeof(float), stream);
  detect_idx_kernel<<<1, 256, 0, stream>>>(Xidx, flag);
  convert_kernel<<<(NRF * DIN) / 256, 256, 0, stream>>>(
      W1mu, W1var, W2mu, W2var, w1mu_bf, w1var_bf, w2mu_bf, w2b_bf, w2var_bf);
  fused_kernel<<<NPTS / 32, 256, 0, stream>>>(
      X, Xidx, w1mu_bf, w1var_bf, w2mu_bf, w2b_bf, w2var_bf, flag,
      out, out + (size_t)SGRP * DOUT);
  finalize_kernel<<<(SGRP * DOUT) / 256, 256, 0, stream>>>(
      out, out + (size_t)SGRP * DOUT);
}

// Round 4
// 1251.617 us; speedup vs baseline: 1.0173x; 1.0173x over previous
//
#include <hip/hip_runtime.h>

// DGP-RF embeddings, fused MFMA implementation. Round 4.
// R4 thesis: stop chasing occupancy (R2/R3 showed every block/CU beyond 2
// thrashes the 1.78 MB weight set out of the 4 MB/XCD L2: FETCH 73->240->1009
// MB as blk/CU went 2->3->4). Instead, fix per-wave ILP at 2 blk/CU:
//  (a) X A-fragments are chunk-invariant -> load to registers ONCE (16
//      ds_read_b128), not per chunk. Squared fragment recomputed per k.
//  (b) explicit 2-deep register double-buffer on ALL weight (B) loads; GEMM2
//      B preloaded during moments math; next chunk's GEMM1 B preloaded during
//      GEMM2 tail. R3's VGPR_Count=64 showed the compiler was issuing loads
//      just-in-time (zero prefetch) under the launch_bounds squeeze.
//  (c) __launch_bounds__(256,2): pin the good L2 regime, free the allocator.

#define NPTS   131072
#define SGRP   16384
#define DIN    256
#define NRF    1024
#define DOUT   128

#define XLD    264   // 256 + 8 pad (16B-aligned rows)
#define TLD    136   // 128 + 8 pad

typedef __attribute__((ext_vector_type(8))) short bf16x8;
typedef __attribute__((ext_vector_type(4))) float f32x4;
typedef __attribute__((ext_vector_type(2))) float f32x2;
typedef __attribute__((ext_vector_type(4))) float f32x4v;

__device__ __forceinline__ unsigned short f2bf(float f) {
  unsigned u = __float_as_uint(f);
  u += 0x7fffu + ((u >> 16) & 1u);   // round-to-nearest-even
  return (unsigned short)(u >> 16);
}

__device__ __forceinline__ float fast_rcp(float x) {
#if __has_builtin(__builtin_amdgcn_rcpf)
  return __builtin_amdgcn_rcpf(x);
#else
  return 1.0f / x;
#endif
}
__device__ __forceinline__ float fast_rsq(float x) {
#if __has_builtin(__builtin_amdgcn_rsqf)
  return __builtin_amdgcn_rsqf(x);
#else
  return rsqrtf(x);
#endif
}
__device__ __forceinline__ float fast_exp2(float x) {
#if __has_builtin(__builtin_amdgcn_exp2f)
  return __builtin_amdgcn_exp2f(x);
#else
  return exp2f(x);
#endif
}

// elementwise square of a bf16x8 fragment; pk_mul + round-half-up pack.
__device__ __forceinline__ bf16x8 sq_frag(bf16x8 a) {
  union { bf16x8 h; unsigned u[4]; } in, out;
  in.h = a;
#pragma unroll
  for (int i = 0; i < 4; ++i) {
    unsigned w = in.u[i];
    f32x2 f;
    f[0] = __uint_as_float(w << 16);
    f[1] = __uint_as_float(w & 0xffff0000u);
    f32x2 s = f * f;                                   // v_pk_mul_f32
    unsigned lo = (__float_as_uint(s[0]) + 0x8000u) >> 16;
    unsigned hi = (__float_as_uint(s[1]) + 0x8000u) & 0xffff0000u;
    out.u[i] = hi | lo;
  }
  return out.h;
}

// Exact Gaussian-ReLU moments (A&S 7.1.26 erf, one shared exp2).
__device__ __forceinline__ void relu_moments(float mu, float v,
                                             float& mo, float& vo) {
  float vpe = v + 1e-8f;
  float rsq = fast_rsq(vpe);
  float s   = vpe * rsq;
  float z   = mu * rsq;
  float E   = fast_exp2(-0.7213475204444817f * z * z);  // exp(-z^2/2)
  float x   = 0.70710678118654752f * fabsf(z);
  float t   = fast_rcp(fmaf(0.3275911f, x, 1.0f));
  float poly = t * fmaf(t, fmaf(t, fmaf(t, fmaf(t, 1.061405429f, -1.453152027f),
                                        1.421413741f), -0.284496736f), 0.254829592f);
  float q   = 0.5f * poly * E;
  float Phi = (z >= 0.0f) ? (1.0f - q) : q;
  float phi = 0.3989422804014327f * E;
  float sphi = s * phi;
  mo = fmaf(mu, Phi, sphi);
  float ey2 = fmaf(fmaf(mu, mu, v), Phi, mu * sphi);
  vo = fmaxf(fmaf(-mo, mo, ey2), 1e-6f);
}

// ---------------- kernel 0: detect whether X_idx is int32 or int64 -------------
__global__ void detect_idx_kernel(const unsigned* __restrict__ raw,
                                  int* __restrict__ flag) {
  __shared__ int any_nz;
  if (threadIdx.x == 0) any_nz = 0;
  __syncthreads();
  if (raw[2 * threadIdx.x + 1] != 0u) atomicOr(&any_nz, 1);
  __syncthreads();
  if (threadIdx.x == 0) *flag = (any_nz == 0) ? 1 : 0;   // 1 => int64
}

// ---------------- kernel 1: convert weights to bf16 ---------------------------
__global__ __launch_bounds__(256) void convert_kernel(
    const float* __restrict__ W1mu, const float* __restrict__ W1var,
    const float* __restrict__ W2mu, const float* __restrict__ W2var,
    unsigned short* __restrict__ w1mu_bf, unsigned short* __restrict__ w1var_bf,
    unsigned short* __restrict__ w2mu_bf, unsigned short* __restrict__ w2b_bf,
    unsigned short* __restrict__ w2var_bf) {
  int i = blockIdx.x * 256 + threadIdx.x;      // grid covers 262144 exactly
  w1mu_bf[i]  = f2bf(W1mu[i]);
  w1var_bf[i] = f2bf(W1var[i]);
  if (i < NRF * DOUT) {
    float m = W2mu[i];
    float v = W2var[i];
    w2mu_bf[i]  = f2bf(m);
    w2b_bf[i]   = f2bf(fmaf(m, m, v));      // W2mu^2 + W2var
    w2var_bf[i] = f2bf(v);
  }
}

// ---------------- kernel 2: fused DGP-RF block --------------------------------
__global__ __launch_bounds__(256, 2) void fused_kernel(
    const float* __restrict__ X,
    const unsigned* __restrict__ Xidx_raw,
    const unsigned short* __restrict__ W1mu, const unsigned short* __restrict__ W1var,
    const unsigned short* __restrict__ W2mu, const unsigned short* __restrict__ W2b,
    const unsigned short* __restrict__ W2var,
    const int* __restrict__ flag64,
    float* __restrict__ acc_means,   // [S,128] accumulates prec*mo
    float* __restrict__ acc_vars) {  // [S,128] accumulates prec
  __shared__ unsigned short Xb[32 * XLD];
  __shared__ unsigned short Tm[32 * TLD];
  __shared__ unsigned short Tv[32 * TLD];
  __shared__ int sidx[32];

  const int tid = threadIdx.x;
  const int p0  = blockIdx.x * 32;
  const int is64 = *flag64;

  if (tid < 32) {
    int p = p0 + tid;
    sidx[tid] = (int)(is64 ? Xidx_raw[2 * (size_t)p] : Xidx_raw[p]);
  }
  // stage X tile as bf16, nontemporal (single-use stream)
#pragma unroll
  for (int i = 0; i < 8; ++i) {
    int idx4 = i * 256 + tid;       // 0..2047 (32 rows x 64 float4)
    int row  = idx4 >> 6;
    int c4   = idx4 & 63;
    f32x4v xv = __builtin_nontemporal_load(
        (const f32x4v*)(X + (size_t)(p0 + row) * DIN + c4 * 4));
    int off = row * XLD + c4 * 4;
    ushort4 b;
    b.x = f2bf(xv[0]); b.y = f2bf(xv[1]); b.z = f2bf(xv[2]); b.w = f2bf(xv[3]);
    *(ushort4*)(Xb + off) = b;
  }
  __syncthreads();

  const int lane = tid & 63;
  const int wave = tid >> 6;
  const int l16  = lane & 15;
  const int quad = lane >> 4;

  // ---- X A-fragments: chunk-invariant, load to registers ONCE ----
  bf16x8 xf[2][8];
#pragma unroll
  for (int mt = 0; mt < 2; ++mt)
#pragma unroll
    for (int k = 0; k < 8; ++k)
      xf[mt][k] = *(const bf16x8*)(Xb + (mt * 16 + l16) * XLD + k * 32 + quad * 8);

  f32x4 acc_mo[2][2], acc_vo[2][2];
#pragma unroll
  for (int mt = 0; mt < 2; ++mt)
#pragma unroll
    for (int j = 0; j < 2; ++j) {
      acc_mo[mt][j] = (f32x4){0.f, 0.f, 0.f, 0.f};
      acc_vo[mt][j] = (f32x4){0.f, 0.f, 0.f, 0.f};
    }

  const int nrow0 = (wave * 2 + 0) * 16 + l16;   // B rows this wave owns
  const int nrow1 = (wave * 2 + 1) * 16 + l16;
  const int qoff  = quad * 8;

  // GEMM1 B double-buffer (slot = k&1), preloaded for c=0, k=0,1
  bf16x8 g1mu[2][2], g1vr[2][2];
#pragma unroll
  for (int k = 0; k < 2; ++k) {
    size_t o0 = (size_t)nrow0 * DIN + k * 32 + qoff;
    size_t o1 = (size_t)nrow1 * DIN + k * 32 + qoff;
    g1mu[k][0] = *(const bf16x8*)(W1mu + o0);
    g1mu[k][1] = *(const bf16x8*)(W1mu + o1);
    g1vr[k][0] = *(const bf16x8*)(W1var + o0);
    g1vr[k][1] = *(const bf16x8*)(W1var + o1);
  }

#pragma unroll 1
  for (int c = 0; c < 8; ++c) {
    // ---- layer 1: m,v chunk [32 x 128] with 2-deep B pipeline ----
    f32x4 am[2][2], av[2][2];
#pragma unroll
    for (int mt = 0; mt < 2; ++mt)
#pragma unroll
      for (int nt = 0; nt < 2; ++nt) {
        am[mt][nt] = (f32x4){0.f, 0.f, 0.f, 0.f};
        av[mt][nt] = (f32x4){0.f, 0.f, 0.f, 0.f};
      }
    const size_t cbase1 = (size_t)(c * 128) * DIN;   // chunk row offset in W1
#pragma unroll
    for (int k = 0; k < 8; ++k) {
      bf16x8 cmu0 = g1mu[k & 1][0], cmu1 = g1mu[k & 1][1];
      bf16x8 cvr0 = g1vr[k & 1][0], cvr1 = g1vr[k & 1][1];
      if (k < 6) {     // refill slot with k+2
        size_t o0 = cbase1 + (size_t)nrow0 * DIN + (k + 2) * 32 + qoff;
        size_t o1 = cbase1 + (size_t)nrow1 * DIN + (k + 2) * 32 + qoff;
        g1mu[k & 1][0] = *(const bf16x8*)(W1mu + o0);
        g1mu[k & 1][1] = *(const bf16x8*)(W1mu + o1);
        g1vr[k & 1][0] = *(const bf16x8*)(W1var + o0);
        g1vr[k & 1][1] = *(const bf16x8*)(W1var + o1);
      }
#pragma unroll
      for (int mt = 0; mt < 2; ++mt) {
        bf16x8 ax = xf[mt][k];
        bf16x8 aq = sq_frag(ax);
        am[mt][0] = __builtin_amdgcn_mfma_f32_16x16x32_bf16(ax, cmu0, am[mt][0], 0, 0, 0);
        am[mt][1] = __builtin_amdgcn_mfma_f32_16x16x32_bf16(ax, cmu1, am[mt][1], 0, 0, 0);
        av[mt][0] = __builtin_amdgcn_mfma_f32_16x16x32_bf16(aq, cvr0, av[mt][0], 0, 0, 0);
        av[mt][1] = __builtin_amdgcn_mfma_f32_16x16x32_bf16(aq, cvr1, av[mt][1], 0, 0, 0);
      }
    }

    // ---- preload GEMM2 B (k2=0,1) — independent of LDS, overlaps moments ----
    bf16x8 g2m[2][2], g2b[2][2], g2v[2][2];
    const size_t cbase2 = (size_t)(c * 128);
#pragma unroll
    for (int k2 = 0; k2 < 2; ++k2) {
      size_t o0 = (size_t)nrow0 * NRF + cbase2 + k2 * 32 + qoff;
      size_t o1 = (size_t)nrow1 * NRF + cbase2 + k2 * 32 + qoff;
      g2m[k2][0] = *(const bf16x8*)(W2mu + o0);
      g2m[k2][1] = *(const bf16x8*)(W2mu + o1);
      g2b[k2][0] = *(const bf16x8*)(W2b + o0);
      g2b[k2][1] = *(const bf16x8*)(W2b + o1);
      g2v[k2][0] = *(const bf16x8*)(W2var + o0);
      g2v[k2][1] = *(const bf16x8*)(W2var + o1);
    }

    // ---- ReLU moments -> Tm/Tv (C-layout -> A-layout) ----
#pragma unroll
    for (int mt = 0; mt < 2; ++mt)
#pragma unroll
      for (int nt = 0; nt < 2; ++nt) {
        int col = (wave * 2 + nt) * 16 + l16;
#pragma unroll
        for (int r = 0; r < 4; ++r) {
          float mo, vo;
          relu_moments(am[mt][nt][r], av[mt][nt][r], mo, vo);
          int o = (mt * 16 + quad * 4 + r) * TLD + col;
          Tm[o] = f2bf(mo); Tv[o] = f2bf(vo);
        }
      }
    __syncthreads();

    // ---- layer 2 with 2-deep B pipeline ----
#pragma unroll
    for (int k2 = 0; k2 < 4; ++k2) {
      bf16x8 c2m0 = g2m[k2 & 1][0], c2m1 = g2m[k2 & 1][1];
      bf16x8 c2b0 = g2b[k2 & 1][0], c2b1 = g2b[k2 & 1][1];
      bf16x8 c2v0 = g2v[k2 & 1][0], c2v1 = g2v[k2 & 1][1];
      if (k2 < 2) {    // refill slot with k2+2
        size_t o0 = (size_t)nrow0 * NRF + cbase2 + (k2 + 2) * 32 + qoff;
        size_t o1 = (size_t)nrow1 * NRF + cbase2 + (k2 + 2) * 32 + qoff;
        g2m[k2][0] = *(const bf16x8*)(W2mu + o0);
        g2m[k2][1] = *(const bf16x8*)(W2mu + o1);
        g2b[k2][0] = *(const bf16x8*)(W2b + o0);
        g2b[k2][1] = *(const bf16x8*)(W2b + o1);
        g2v[k2][0] = *(const bf16x8*)(W2var + o0);
        g2v[k2][1] = *(const bf16x8*)(W2var + o1);
      }
#pragma unroll
      for (int mt = 0; mt < 2; ++mt) {
        int aoff = (mt * 16 + l16) * TLD + k2 * 32 + qoff;
        bf16x8 fam = *(const bf16x8*)(Tm + aoff);
        bf16x8 fav = *(const bf16x8*)(Tv + aoff);
        bf16x8 fsq = sq_frag(fam);
        acc_mo[mt][0] = __builtin_amdgcn_mfma_f32_16x16x32_bf16(fam, c2m0, acc_mo[mt][0], 0, 0, 0);
        acc_mo[mt][1] = __builtin_amdgcn_mfma_f32_16x16x32_bf16(fam, c2m1, acc_mo[mt][1], 0, 0, 0);
        acc_vo[mt][0] = __builtin_amdgcn_mfma_f32_16x16x32_bf16(fav, c2b0, acc_vo[mt][0], 0, 0, 0);
        acc_vo[mt][1] = __builtin_amdgcn_mfma_f32_16x16x32_bf16(fav, c2b1, acc_vo[mt][1], 0, 0, 0);
        acc_vo[mt][0] = __builtin_amdgcn_mfma_f32_16x16x32_bf16(fsq, c2v0, acc_vo[mt][0], 0, 0, 0);
        acc_vo[mt][1] = __builtin_amdgcn_mfma_f32_16x16x32_bf16(fsq, c2v1, acc_vo[mt][1], 0, 0, 0);
      }
    }

    // ---- preload next chunk's GEMM1 B (k=0,1) before the barrier ----
    if (c < 7) {
      const size_t nbase1 = (size_t)((c + 1) * 128) * DIN;
#pragma unroll
      for (int k = 0; k < 2; ++k) {
        size_t o0 = nbase1 + (size_t)nrow0 * DIN + k * 32 + qoff;
        size_t o1 = nbase1 + (size_t)nrow1 * DIN + k * 32 + qoff;
        g1mu[k][0] = *(const bf16x8*)(W1mu + o0);
        g1mu[k][1] = *(const bf16x8*)(W1mu + o1);
        g1vr[k][0] = *(const bf16x8*)(W1var + o0);
        g1vr[k][1] = *(const bf16x8*)(W1var + o1);
      }
    }
    __syncthreads();
  }

  // ---- epilogue: precision-weighted scatter ----
#pragma unroll
  for (int mt = 0; mt < 2; ++mt)
#pragma unroll
    for (int j = 0; j < 2; ++j) {
      int dim = (wave * 2 + j) * 16 + l16;
#pragma unroll
      for (int r = 0; r < 4; ++r) {
        int prow = mt * 16 + quad * 4 + r;
        float mo = acc_mo[mt][j][r];
        float vo = acc_vo[mt][j][r];
        float prec = fast_rcp(vo);
        size_t o = (size_t)sidx[prow] * DOUT + dim;
        unsafeAtomicAdd(acc_means + o, prec * mo);
        unsafeAtomicAdd(acc_vars + o, prec);
      }
    }
}

// ---------------- kernel 3: finalize ------------------------------------------
__global__ __launch_bounds__(256) void finalize_kernel(float* __restrict__ means,
                                                       float* __restrict__ vars) {
  int i = blockIdx.x * 256 + threadIdx.x;   // covers S*DOUT exactly
  float p  = vars[i];
  float pm = means[i];
  float var = 1.0f / p;
  means[i] = pm * var;
  vars[i]  = var;
}

extern "C" void kernel_launch(void* const* d_in, const int* in_sizes, int n_in,
                              void* d_out, int out_size, void* d_ws, size_t ws_size,
                              hipStream_t stream) {
  const float*    X     = (const float*)d_in[0];
  const unsigned* Xidx  = (const unsigned*)d_in[1];
  const float*    W1mu  = (const float*)d_in[2];
  const float*    W1var = (const float*)d_in[3];
  const float*    W2mu  = (const float*)d_in[4];
  const float*    W2var = (const float*)d_in[5];
  float* out = (float*)d_out;

  unsigned short* w1mu_bf  = (unsigned short*)d_ws;
  unsigned short* w1var_bf = w1mu_bf + NRF * DIN;       // 262144
  unsigned short* w2mu_bf  = w1var_bf + NRF * DIN;
  unsigned short* w2b_bf   = w2mu_bf + NRF * DOUT;      // 131072
  unsigned short* w2var_bf = w2b_bf + NRF * DOUT;
  int* flag = (int*)(w2var_bf + NRF * DOUT);

  hipMemsetAsync(d_out, 0, (size_t)out_size * sizeof(float), stream);
  detect_idx_kernel<<<1, 256, 0, stream>>>(Xidx, flag);
  convert_kernel<<<(NRF * DIN) / 256, 256, 0, stream>>>(
      W1mu, W1var, W2mu, W2var, w1mu_bf, w1var_bf, w2mu_bf, w2b_bf, w2var_bf);
  fused_kernel<<<NPTS / 32, 256, 0, stream>>>(
      X, Xidx, w1mu_bf, w1var_bf, w2mu_bf, w2b_bf, w2var_bf, flag,
      out, out + (size_t)SGRP * DOUT);
  finalize_kernel<<<(SGRP * DOUT) / 256, 256, 0, stream>>>(
      out, out + (size_t)SGRP * DOUT);
}

// Round 5
// 714.893 us; speedup vs baseline: 1.7810x; 1.7508x over previous
//
#include <hip/hip_runtime.h>

// DGP-RF embeddings, fused MFMA implementation. Round 5.
// R5 thesis: R1-R4 all ~1000us with <30% pipe utilization because arithmetic
// intensity per weight load is too low (2 MFMAs per 16B load at M=32) and
// every extra resident WG adds a whole new 1.75MB L2 weight stream (FETCH
// 73->240->1009 MB at 2->3->4 blk/CU). So: M=64 points per WG (2048 WGs):
//   - 4 MFMAs per GEMM1 B-load, half the total L2 weight traffic (3.6GB),
//   - X loads back to NORMAL (R4's nontemporal bypassed the L3 that absorbed
//     X in R1: FETCH 73->164MB),
//   - preloads issued >=1000cyc before barriers (drain becomes free),
//   - 2nd barrier moved to just before Tm/Tv writes (max inter-wave skew).

#define NPTS   131072
#define SGRP   16384
#define DIN    256
#define NRF    1024
#define DOUT   128
#define MT     64            // points per WG
#define NWG    (NPTS / MT)   // 2048

#define XLD    264   // 256 + 8 pad (16B-aligned rows)
#define TLD    136   // 128 + 8 pad

typedef __attribute__((ext_vector_type(8))) short bf16x8;
typedef __attribute__((ext_vector_type(4))) float f32x4;
typedef __attribute__((ext_vector_type(2))) float f32x2;
typedef __attribute__((ext_vector_type(4))) float f32x4v;

__device__ __forceinline__ unsigned short f2bf(float f) {
  unsigned u = __float_as_uint(f);
  u += 0x7fffu + ((u >> 16) & 1u);   // round-to-nearest-even
  return (unsigned short)(u >> 16);
}

__device__ __forceinline__ float fast_rcp(float x) {
#if __has_builtin(__builtin_amdgcn_rcpf)
  return __builtin_amdgcn_rcpf(x);
#else
  return 1.0f / x;
#endif
}
__device__ __forceinline__ float fast_rsq(float x) {
#if __has_builtin(__builtin_amdgcn_rsqf)
  return __builtin_amdgcn_rsqf(x);
#else
  return rsqrtf(x);
#endif
}
__device__ __forceinline__ float fast_exp2(float x) {
#if __has_builtin(__builtin_amdgcn_exp2f)
  return __builtin_amdgcn_exp2f(x);
#else
  return exp2f(x);
#endif
}

// elementwise square of a bf16x8 fragment; pk_mul + round-half-up pack.
__device__ __forceinline__ bf16x8 sq_frag(bf16x8 a) {
  union { bf16x8 h; unsigned u[4]; } in, out;
  in.h = a;
#pragma unroll
  for (int i = 0; i < 4; ++i) {
    unsigned w = in.u[i];
    f32x2 f;
    f[0] = __uint_as_float(w << 16);
    f[1] = __uint_as_float(w & 0xffff0000u);
    f32x2 s = f * f;                                   // v_pk_mul_f32
    unsigned lo = (__float_as_uint(s[0]) + 0x8000u) >> 16;
    unsigned hi = (__float_as_uint(s[1]) + 0x8000u) & 0xffff0000u;
    out.u[i] = hi | lo;
  }
  return out.h;
}

// Exact Gaussian-ReLU moments (A&S 7.1.26 erf, one shared exp2).
__device__ __forceinline__ void relu_moments(float mu, float v,
                                             float& mo, float& vo) {
  float vpe = v + 1e-8f;
  float rsq = fast_rsq(vpe);
  float s   = vpe * rsq;
  float z   = mu * rsq;
  float E   = fast_exp2(-0.7213475204444817f * z * z);  // exp(-z^2/2)
  float x   = 0.70710678118654752f * fabsf(z);
  float t   = fast_rcp(fmaf(0.3275911f, x, 1.0f));
  float poly = t * fmaf(t, fmaf(t, fmaf(t, fmaf(t, 1.061405429f, -1.453152027f),
                                        1.421413741f), -0.284496736f), 0.254829592f);
  float q   = 0.5f * poly * E;
  float Phi = (z >= 0.0f) ? (1.0f - q) : q;
  float phi = 0.3989422804014327f * E;
  float sphi = s * phi;
  mo = fmaf(mu, Phi, sphi);
  float ey2 = fmaf(fmaf(mu, mu, v), Phi, mu * sphi);
  vo = fmaxf(fmaf(-mo, mo, ey2), 1e-6f);
}

// ---------------- kernel 0: detect whether X_idx is int32 or int64 -------------
__global__ void detect_idx_kernel(const unsigned* __restrict__ raw,
                                  int* __restrict__ flag) {
  __shared__ int any_nz;
  if (threadIdx.x == 0) any_nz = 0;
  __syncthreads();
  if (raw[2 * threadIdx.x + 1] != 0u) atomicOr(&any_nz, 1);
  __syncthreads();
  if (threadIdx.x == 0) *flag = (any_nz == 0) ? 1 : 0;   // 1 => int64
}

// ---------------- kernel 1: convert weights to bf16 ---------------------------
__global__ __launch_bounds__(256) void convert_kernel(
    const float* __restrict__ W1mu, const float* __restrict__ W1var,
    const float* __restrict__ W2mu, const float* __restrict__ W2var,
    unsigned short* __restrict__ w1mu_bf, unsigned short* __restrict__ w1var_bf,
    unsigned short* __restrict__ w2mu_bf, unsigned short* __restrict__ w2b_bf,
    unsigned short* __restrict__ w2var_bf) {
  int i = blockIdx.x * 256 + threadIdx.x;      // grid covers 262144 exactly
  w1mu_bf[i]  = f2bf(W1mu[i]);
  w1var_bf[i] = f2bf(W1var[i]);
  if (i < NRF * DOUT) {
    float m = W2mu[i];
    float v = W2var[i];
    w2mu_bf[i]  = f2bf(m);
    w2b_bf[i]   = f2bf(fmaf(m, m, v));      // W2mu^2 + W2var
    w2var_bf[i] = f2bf(v);
  }
}

// ---------------- kernel 2: fused DGP-RF block --------------------------------
__global__ __launch_bounds__(256, 2) void fused_kernel(
    const float* __restrict__ X,
    const unsigned* __restrict__ Xidx_raw,
    const unsigned short* __restrict__ W1mu, const unsigned short* __restrict__ W1var,
    const unsigned short* __restrict__ W2mu, const unsigned short* __restrict__ W2b,
    const unsigned short* __restrict__ W2var,
    const int* __restrict__ flag64,
    float* __restrict__ acc_means,   // [S,128] accumulates prec*mo
    float* __restrict__ acc_vars) {  // [S,128] accumulates prec
  __shared__ unsigned short Xb[MT * XLD];    // 33.8 KB
  __shared__ unsigned short Tm[MT * TLD];    // 17.4 KB
  __shared__ unsigned short Tv[MT * TLD];    // 17.4 KB
  __shared__ int sidx[MT];

  const int tid = threadIdx.x;
  const int p0  = blockIdx.x * MT;
  const int is64 = *flag64;

  if (tid < MT) {
    int p = p0 + tid;
    sidx[tid] = (int)(is64 ? Xidx_raw[2 * (size_t)p] : Xidx_raw[p]);
  }
  // stage X tile as bf16 (normal loads: X is L3-resident across replays)
#pragma unroll
  for (int i = 0; i < 16; ++i) {
    int idx4 = i * 256 + tid;       // 0..4095 (64 rows x 64 float4)
    int row  = idx4 >> 6;
    int c4   = idx4 & 63;
    f32x4v xv = *(const f32x4v*)(X + (size_t)(p0 + row) * DIN + c4 * 4);
    int off = row * XLD + c4 * 4;
    ushort4 b;
    b.x = f2bf(xv[0]); b.y = f2bf(xv[1]); b.z = f2bf(xv[2]); b.w = f2bf(xv[3]);
    *(ushort4*)(Xb + off) = b;
  }
  __syncthreads();

  const int lane = tid & 63;
  const int wave = tid >> 6;
  const int l16  = lane & 15;
  const int quad = lane >> 4;
  const int qoff = quad * 8;

  const int nrow0 = (wave * 2 + 0) * 16 + l16;   // B rows this wave owns
  const int nrow1 = (wave * 2 + 1) * 16 + l16;

  f32x4 acc_mo[4][2], acc_vo[4][2];
#pragma unroll
  for (int mt = 0; mt < 4; ++mt)
#pragma unroll
    for (int j = 0; j < 2; ++j) {
      acc_mo[mt][j] = (f32x4){0.f, 0.f, 0.f, 0.f};
      acc_vo[mt][j] = (f32x4){0.f, 0.f, 0.f, 0.f};
    }

  // GEMM1 B double-buffer (slot = k&1), preloaded for c=0, k=0,1
  bf16x8 g1mu[2][2], g1vr[2][2];
#pragma unroll
  for (int k = 0; k < 2; ++k) {
    size_t o0 = (size_t)nrow0 * DIN + k * 32 + qoff;
    size_t o1 = (size_t)nrow1 * DIN + k * 32 + qoff;
    g1mu[k][0] = *(const bf16x8*)(W1mu + o0);
    g1mu[k][1] = *(const bf16x8*)(W1mu + o1);
    g1vr[k][0] = *(const bf16x8*)(W1var + o0);
    g1vr[k][1] = *(const bf16x8*)(W1var + o1);
  }

#pragma unroll 1
  for (int c = 0; c < 8; ++c) {
    // ---- layer 1: m,v chunk [64 x 128] ----
    f32x4 am[4][2], av[4][2];
#pragma unroll
    for (int mt = 0; mt < 4; ++mt)
#pragma unroll
      for (int nt = 0; nt < 2; ++nt) {
        am[mt][nt] = (f32x4){0.f, 0.f, 0.f, 0.f};
        av[mt][nt] = (f32x4){0.f, 0.f, 0.f, 0.f};
      }
    const size_t cbase1 = (size_t)(c * 128) * DIN;
#pragma unroll
    for (int k = 0; k < 8; ++k) {
      bf16x8 cmu0 = g1mu[k & 1][0], cmu1 = g1mu[k & 1][1];
      bf16x8 cvr0 = g1vr[k & 1][0], cvr1 = g1vr[k & 1][1];
      if (k < 6) {     // refill slot with k+2
        size_t o0 = cbase1 + (size_t)nrow0 * DIN + (k + 2) * 32 + qoff;
        size_t o1 = cbase1 + (size_t)nrow1 * DIN + (k + 2) * 32 + qoff;
        g1mu[k & 1][0] = *(const bf16x8*)(W1mu + o0);
        g1mu[k & 1][1] = *(const bf16x8*)(W1mu + o1);
        g1vr[k & 1][0] = *(const bf16x8*)(W1var + o0);
        g1vr[k & 1][1] = *(const bf16x8*)(W1var + o1);
      }
#pragma unroll
      for (int mt = 0; mt < 4; ++mt) {
        bf16x8 ax = *(const bf16x8*)(Xb + (mt * 16 + l16) * XLD + k * 32 + qoff);
        bf16x8 aq = sq_frag(ax);
        am[mt][0] = __builtin_amdgcn_mfma_f32_16x16x32_bf16(ax, cmu0, am[mt][0], 0, 0, 0);
        am[mt][1] = __builtin_amdgcn_mfma_f32_16x16x32_bf16(ax, cmu1, am[mt][1], 0, 0, 0);
        av[mt][0] = __builtin_amdgcn_mfma_f32_16x16x32_bf16(aq, cvr0, av[mt][0], 0, 0, 0);
        av[mt][1] = __builtin_amdgcn_mfma_f32_16x16x32_bf16(aq, cvr1, av[mt][1], 0, 0, 0);
      }
    }

    // ---- preload next chunk's GEMM1 B (k=0,1): hidden by moments+GEMM2 ----
    if (c < 7) {
      const size_t nbase1 = (size_t)((c + 1) * 128) * DIN;
#pragma unroll
      for (int k = 0; k < 2; ++k) {
        size_t o0 = nbase1 + (size_t)nrow0 * DIN + k * 32 + qoff;
        size_t o1 = nbase1 + (size_t)nrow1 * DIN + k * 32 + qoff;
        g1mu[k][0] = *(const bf16x8*)(W1mu + o0);
        g1mu[k][1] = *(const bf16x8*)(W1mu + o1);
        g1vr[k][0] = *(const bf16x8*)(W1var + o0);
        g1vr[k][1] = *(const bf16x8*)(W1var + o1);
      }
    }

    // ---- preload GEMM2 B (k2=0,1): hidden by moments math ----
    bf16x8 g2m[2][2], g2b[2][2], g2v[2][2];
    const size_t cbase2 = (size_t)(c * 128);
#pragma unroll
    for (int k2 = 0; k2 < 2; ++k2) {
      size_t o0 = (size_t)nrow0 * NRF + cbase2 + k2 * 32 + qoff;
      size_t o1 = (size_t)nrow1 * NRF + cbase2 + k2 * 32 + qoff;
      g2m[k2][0] = *(const bf16x8*)(W2mu + o0);
      g2m[k2][1] = *(const bf16x8*)(W2mu + o1);
      g2b[k2][0] = *(const bf16x8*)(W2b + o0);
      g2b[k2][1] = *(const bf16x8*)(W2b + o1);
      g2v[k2][0] = *(const bf16x8*)(W2var + o0);
      g2v[k2][1] = *(const bf16x8*)(W2var + o1);
    }

    // Barrier A: all GEMM2(c-1) reads of Tm/Tv complete before we overwrite.
    // Placed here (not after GEMM2) so waves skew freely through GEMM1.
    __syncthreads();

    // ---- ReLU moments -> Tm/Tv (C-layout -> A-layout) ----
#pragma unroll
    for (int mt = 0; mt < 4; ++mt)
#pragma unroll
      for (int nt = 0; nt < 2; ++nt) {
        int col = (wave * 2 + nt) * 16 + l16;
#pragma unroll
        for (int r = 0; r < 4; ++r) {
          float mo, vo;
          relu_moments(am[mt][nt][r], av[mt][nt][r], mo, vo);
          int o = (mt * 16 + quad * 4 + r) * TLD + col;
          Tm[o] = f2bf(mo); Tv[o] = f2bf(vo);
        }
      }
    // Barrier B: writes visible before reads.
    __syncthreads();

    // ---- layer 2 with 2-deep B pipeline ----
#pragma unroll
    for (int k2 = 0; k2 < 4; ++k2) {
      bf16x8 c2m0 = g2m[k2 & 1][0], c2m1 = g2m[k2 & 1][1];
      bf16x8 c2b0 = g2b[k2 & 1][0], c2b1 = g2b[k2 & 1][1];
      bf16x8 c2v0 = g2v[k2 & 1][0], c2v1 = g2v[k2 & 1][1];
      if (k2 < 2) {    // refill slot with k2+2
        size_t o0 = (size_t)nrow0 * NRF + cbase2 + (k2 + 2) * 32 + qoff;
        size_t o1 = (size_t)nrow1 * NRF + cbase2 + (k2 + 2) * 32 + qoff;
        g2m[k2][0] = *(const bf16x8*)(W2mu + o0);
        g2m[k2][1] = *(const bf16x8*)(W2mu + o1);
        g2b[k2][0] = *(const bf16x8*)(W2b + o0);
        g2b[k2][1] = *(const bf16x8*)(W2b + o1);
        g2v[k2][0] = *(const bf16x8*)(W2var + o0);
        g2v[k2][1] = *(const bf16x8*)(W2var + o1);
      }
#pragma unroll
      for (int mt = 0; mt < 4; ++mt) {
        int aoff = (mt * 16 + l16) * TLD + k2 * 32 + qoff;
        bf16x8 fam = *(const bf16x8*)(Tm + aoff);
        bf16x8 fav = *(const bf16x8*)(Tv + aoff);
        bf16x8 fsq = sq_frag(fam);
        acc_mo[mt][0] = __builtin_amdgcn_mfma_f32_16x16x32_bf16(fam, c2m0, acc_mo[mt][0], 0, 0, 0);
        acc_mo[mt][1] = __builtin_amdgcn_mfma_f32_16x16x32_bf16(fam, c2m1, acc_mo[mt][1], 0, 0, 0);
        acc_vo[mt][0] = __builtin_amdgcn_mfma_f32_16x16x32_bf16(fav, c2b0, acc_vo[mt][0], 0, 0, 0);
        acc_vo[mt][1] = __builtin_amdgcn_mfma_f32_16x16x32_bf16(fav, c2b1, acc_vo[mt][1], 0, 0, 0);
        acc_vo[mt][0] = __builtin_amdgcn_mfma_f32_16x16x32_bf16(fsq, c2v0, acc_vo[mt][0], 0, 0, 0);
        acc_vo[mt][1] = __builtin_amdgcn_mfma_f32_16x16x32_bf16(fsq, c2v1, acc_vo[mt][1], 0, 0, 0);
      }
    }
  }

  // ---- epilogue: precision-weighted scatter ----
#pragma unroll
  for (int mt = 0; mt < 4; ++mt)
#pragma unroll
    for (int j = 0; j < 2; ++j) {
      int dim = (wave * 2 + j) * 16 + l16;
#pragma unroll
      for (int r = 0; r < 4; ++r) {
        int prow = mt * 16 + quad * 4 + r;
        float mo = acc_mo[mt][j][r];
        float vo = acc_vo[mt][j][r];
        float prec = fast_rcp(vo);
        size_t o = (size_t)sidx[prow] * DOUT + dim;
        unsafeAtomicAdd(acc_means + o, prec * mo);
        unsafeAtomicAdd(acc_vars + o, prec);
      }
    }
}

// ---------------- kernel 3: finalize ------------------------------------------
__global__ __launch_bounds__(256) void finalize_kernel(float* __restrict__ means,
                                                       float* __restrict__ vars) {
  int i = blockIdx.x * 256 + threadIdx.x;   // covers S*DOUT exactly
  float p  = vars[i];
  float pm = means[i];
  float var = 1.0f / p;
  means[i] = pm * var;
  vars[i]  = var;
}

extern "C" void kernel_launch(void* const* d_in, const int* in_sizes, int n_in,
                              void* d_out, int out_size, void* d_ws, size_t ws_size,
                              hipStream_t stream) {
  const float*    X     = (const float*)d_in[0];
  const unsigned* Xidx  = (const unsigned*)d_in[1];
  const float*    W1mu  = (const float*)d_in[2];
  const float*    W1var = (const float*)d_in[3];
  const float*    W2mu  = (const float*)d_in[4];
  const float*    W2var = (const float*)d_in[5];
  float* out = (float*)d_out;

  unsigned short* w1mu_bf  = (unsigned short*)d_ws;
  unsigned short* w1var_bf = w1mu_bf + NRF * DIN;       // 262144
  unsigned short* w2mu_bf  = w1var_bf + NRF * DIN;
  unsigned short* w2b_bf   = w2mu_bf + NRF * DOUT;      // 131072
  unsigned short* w2var_bf = w2b_bf + NRF * DOUT;
  int* flag = (int*)(w2var_bf + NRF * DOUT);

  hipMemsetAsync(d_out, 0, (size_t)out_size * sizeof(float), stream);
  detect_idx_kernel<<<1, 256, 0, stream>>>(Xidx, flag);
  convert_kernel<<<(NRF * DIN) / 256, 256, 0, stream>>>(
      W1mu, W1var, W2mu, W2var, w1mu_bf, w1var_bf, w2mu_bf, w2b_bf, w2var_bf);
  fused_kernel<<<NWG, 256, 0, stream>>>(
      X, Xidx, w1mu_bf, w1var_bf, w2mu_bf, w2b_bf, w2var_bf, flag,
      out, out + (size_t)SGRP * DOUT);
  finalize_kernel<<<(SGRP * DOUT) / 256, 256, 0, stream>>>(
      out, out + (size_t)SGRP * DOUT);
}